// Round 1
// baseline (2213.688 us; speedup 1.0000x reference)
//
#include <hip/hip_runtime.h>
#include <math.h>

// Problem sizes (fixed by setup_inputs)
constexpr int N_V  = 16384;       // original vertices
constexpr int N_F  = 16384;       // original faces
constexpr int G_F  = 8192;        // simplified faces
constexpr int NS   = 16;          // samples per face
constexpr int NPTS = G_F * NS;    // 131072 sample points

// Workspace layout (float4 units for vector arrays, then raw floats)
constexpr int WS_VERT  = 1;                  // [N_V]  x,y,z,|v|^2
constexpr int WS_OBARY = WS_VERT + N_V;      // [N_F]  orig barycenters + sq
constexpr int WS_SBARY = WS_OBARY + N_F;     // [G_F]  simp barycenters + sq
constexpr int WS_PTS   = WS_SBARY + G_F;     // [NPTS] sample points + sq
constexpr int WS_F4_TOTAL = WS_PTS + NPTS;
constexpr int WS_MINF = WS_F4_TOTAL * 4;     // [G_F]  fwd min d^2
constexpr int WS_MINR = WS_MINF + G_F;       // [NPTS] rev min d^2
// total floats: ~794628 (~3.03 MB)

__global__ void k_init(float* __restrict__ ws) {
  int i = blockIdx.x * blockDim.x + threadIdx.x;
  if (i < 4) ws[i] = 0.0f;                                   // accumulators
  if (i < G_F) ws[WS_MINF + i] = __uint_as_float(0x7f800000u); // +inf
}

__global__ void k_prep_verts(const float* __restrict__ ov, float4* __restrict__ v4) {
  int i = blockIdx.x * blockDim.x + threadIdx.x;
  if (i >= N_V) return;
  float x = ov[3*i], y = ov[3*i+1], z = ov[3*i+2];
  v4[i] = make_float4(x, y, z, fmaf(x, x, fmaf(y, y, z*z)));
}

__global__ void k_obary(const float* __restrict__ ov, const int* __restrict__ of,
                        float4* __restrict__ b4) {
  int i = blockIdx.x * blockDim.x + threadIdx.x;
  if (i >= N_F) return;
  int a = of[3*i], b = of[3*i+1], c = of[3*i+2];
  float x = (ov[3*a] + ov[3*b] + ov[3*c]) * (1.0f/3.0f);
  float y = (ov[3*a+1] + ov[3*b+1] + ov[3*c+1]) * (1.0f/3.0f);
  float z = (ov[3*a+2] + ov[3*b+2] + ov[3*c+2]) * (1.0f/3.0f);
  b4[i] = make_float4(x, y, z, fmaf(x, x, fmaf(y, y, z*z)));
}

__global__ void k_sbary(const float* __restrict__ sv, const int* __restrict__ sf,
                        float4* __restrict__ b4) {
  int i = blockIdx.x * blockDim.x + threadIdx.x;
  if (i >= G_F) return;
  int a = sf[3*i], b = sf[3*i+1], c = sf[3*i+2];
  float x = (sv[3*a] + sv[3*b] + sv[3*c]) * (1.0f/3.0f);
  float y = (sv[3*a+1] + sv[3*b+1] + sv[3*c+1]) * (1.0f/3.0f);
  float z = (sv[3*a+2] + sv[3*b+2] + sv[3*c+2]) * (1.0f/3.0f);
  b4[i] = make_float4(x, y, z, fmaf(x, x, fmaf(y, y, z*z)));
}

__global__ void k_pts(const float* __restrict__ sv, const int* __restrict__ sf,
                      const float* __restrict__ r1, const float* __restrict__ r2,
                      float4* __restrict__ p4) {
  int i = blockIdx.x * blockDim.x + threadIdx.x;
  if (i >= NPTS) return;
  int g = i >> 4;
  int a = sf[3*g], b = sf[3*g+1], c = sf[3*g+2];
  float sr = sqrtf(r1[i]);
  float u = 1.0f - sr;
  float v = sr * (1.0f - r2[i]);
  float w = sr * r2[i];
  float px = u*sv[3*a]   + v*sv[3*b]   + w*sv[3*c];
  float py = u*sv[3*a+1] + v*sv[3*b+1] + w*sv[3*c+1];
  float pz = u*sv[3*a+2] + v*sv[3*b+2] + w*sv[3*c+2];
  p4[i] = make_float4(px, py, pz, fmaf(px, px, fmaf(py, py, pz*pz)));
}

// forward: min over N_F orig barycenters for each of G_F simp barycenters.
// blockIdx.y selects one of 8 vertex chunks; combine via uint-bit atomicMin
// (valid: d^2 clamped >= 0).
__global__ void k_fwd(const float4* __restrict__ ob, const float4* __restrict__ sb,
                      float* __restrict__ minf) {
  int g = blockIdx.x * blockDim.x + threadIdx.x;
  float4 p = sb[g];
  int k0 = blockIdx.y * (N_F / 8);
  float m = __uint_as_float(0x7f800000u);
  #pragma unroll 8
  for (int k = k0; k < k0 + N_F / 8; ++k) {
    float4 v = ob[k];  // wave-uniform address -> scalar load path
    float dot = fmaf(p.x, v.x, fmaf(p.y, v.y, p.z * v.z));
    m = fminf(m, fmaf(-2.0f, dot, v.w));
  }
  float d2 = fmaxf(p.w + m, 0.0f);
  atomicMin((unsigned int*)&minf[g], __float_as_uint(d2));
}

// reverse: min over all N_V original vertices for each of NPTS sample points.
__global__ void k_rev(const float4* __restrict__ vv, const float4* __restrict__ pp,
                      float* __restrict__ minr) {
  int i = blockIdx.x * blockDim.x + threadIdx.x;
  float4 p = pp[i];
  float m = __uint_as_float(0x7f800000u);
  #pragma unroll 8
  for (int k = 0; k < N_V; ++k) {
    float4 v = vv[k];  // wave-uniform address -> scalar load path
    float dot = fmaf(p.x, v.x, fmaf(p.y, v.y, p.z * v.z));
    m = fminf(m, fmaf(-2.0f, dot, v.w));
  }
  minr[i] = fmaxf(p.w + m, 0.0f);
}

__device__ __forceinline__ float waveSum(float v) {
  #pragma unroll
  for (int o = 32; o > 0; o >>= 1) v += __shfl_down(v, o, 64);
  return v;
}
__device__ __forceinline__ float waveMax(float v) {
  #pragma unroll
  for (int o = 32; o > 0; o >>= 1) v = fmaxf(v, __shfl_down(v, o, 64));
  return v;
}

__global__ void k_reduce(const float* __restrict__ probs, const float* __restrict__ minf,
                         const float* __restrict__ minr, float* __restrict__ acc) {
  int tid = blockIdx.x * blockDim.x + threadIdx.x;
  int stride = gridDim.x * blockDim.x;
  float sf = 0.0f, sr = 0.0f, mx = 0.0f;
  for (int i = tid; i < NPTS; i += stride) {
    float d = sqrtf(fmaxf(minr[i], 1e-12f));
    sr = fmaf(probs[i >> 4], d, sr);
    mx = fmaxf(mx, d);
    if (i < G_F) {
      float df = sqrtf(fmaxf(minf[i], 1e-12f));
      sf = fmaf(probs[i], df, sf);
      sf = fmaf(1e-4f, 1.0f - probs[i], sf);
    }
  }
  __shared__ float lf[4], lr[4], lm[4];
  int lane = threadIdx.x & 63, wid = threadIdx.x >> 6;
  sf = waveSum(sf); sr = waveSum(sr); mx = waveMax(mx);
  if (lane == 0) { lf[wid] = sf; lr[wid] = sr; lm[wid] = mx; }
  __syncthreads();
  if (wid == 0) {
    float a = (lane < 4) ? lf[lane] : 0.0f;
    float b = (lane < 4) ? lr[lane] : 0.0f;
    float c = (lane < 4) ? lm[lane] : 0.0f;
    a = waveSum(a); b = waveSum(b); c = waveMax(c);
    if (lane == 0) {
      atomicAdd(&acc[0], a);
      atomicAdd(&acc[1], b);
      atomicMax((unsigned int*)&acc[2], __float_as_uint(c));
    }
  }
}

__global__ void k_final(const float* __restrict__ acc, float* __restrict__ out) {
  float maxd = acc[2] + 1e-8f;
  out[0] = acc[0] + acc[1] * 0.1f / maxd;
}

extern "C" void kernel_launch(void* const* d_in, const int* in_sizes, int n_in,
                              void* d_out, int out_size, void* d_ws, size_t ws_size,
                              hipStream_t stream) {
  const float* ov    = (const float*)d_in[0];
  const int*   of    = (const int*)  d_in[1];
  const float* sv    = (const float*)d_in[2];
  const int*   sfc   = (const int*)  d_in[3];
  const float* probs = (const float*)d_in[4];
  const float* r1    = (const float*)d_in[5];
  const float* r2    = (const float*)d_in[6];
  float*  ws  = (float*)d_ws;
  float4* ws4 = (float4*)d_ws;
  float*  out = (float*)d_out;

  float*  acc  = ws;                // 4 floats
  float4* v4   = ws4 + WS_VERT;
  float4* ob   = ws4 + WS_OBARY;
  float4* sb   = ws4 + WS_SBARY;
  float4* pp   = ws4 + WS_PTS;
  float*  minf = ws + WS_MINF;
  float*  minr = ws + WS_MINR;

  k_init<<<G_F/256, 256, 0, stream>>>(ws);
  k_prep_verts<<<N_V/256, 256, 0, stream>>>(ov, v4);
  k_obary<<<N_F/256, 256, 0, stream>>>(ov, of, ob);
  k_sbary<<<G_F/256, 256, 0, stream>>>(sv, sfc, sb);
  k_pts<<<NPTS/256, 256, 0, stream>>>(sv, sfc, r1, r2, pp);
  k_fwd<<<dim3(G_F/256, 8), 256, 0, stream>>>(ob, sb, minf);
  k_rev<<<NPTS/256, 256, 0, stream>>>(v4, pp, minr);
  k_reduce<<<256, 256, 0, stream>>>(probs, minf, minr, acc);
  k_final<<<1, 1, 0, stream>>>(acc, out);
}

// Round 2
// 333.150 us; speedup vs baseline: 6.6447x; 6.6447x over previous
//
#include <hip/hip_runtime.h>
#include <math.h>

// Problem sizes (fixed by setup_inputs)
constexpr int N_V  = 16384;       // original vertices
constexpr int N_F  = 16384;       // original faces
constexpr int G_F  = 8192;        // simplified faces
constexpr int NS   = 16;          // samples per face
constexpr int NPTS = G_F * NS;    // 131072 sample points

// k-split factors (occupancy: need >= 8 blocks/CU resident)
constexpr int KS_REV = 16;        // k_rev: 128 x 16 = 2048 blocks, chunk = 1024 verts (16 KB, sL1-resident)
constexpr int KS_FWD = 64;        // k_fwd:  16 x 64 = 1024 blocks, chunk = 256 faces

// Workspace layout (float4 units for vector arrays, then raw floats)
constexpr int WS_VERT  = 1;                  // [N_V]  -2x,-2y,-2z,|v|^2
constexpr int WS_OBARY = WS_VERT + N_V;      // [N_F]  -2x,-2y,-2z,|b|^2 (targets)
constexpr int WS_SBARY = WS_OBARY + N_F;     // [G_F]  x,y,z,|b|^2 (queries)
constexpr int WS_PTS   = WS_SBARY + G_F;     // [NPTS] x,y,z,|p|^2 (queries)
constexpr int WS_F4_TOTAL = WS_PTS + NPTS;
constexpr int WS_MINF = WS_F4_TOTAL * 4;     // [G_F]  fwd min d^2 (uint bits)
constexpr int WS_MINR = WS_MINF + G_F;       // [NPTS] rev min d^2 (uint bits)

__global__ void k_init(unsigned int* __restrict__ ws) {
  int i = blockIdx.x * blockDim.x + threadIdx.x;
  if (i < 4) ws[i] = 0u;                          // float accumulators (0.0f)
  if (i < G_F) ws[WS_MINF + i] = 0x7f800000u;     // +inf
  ws[WS_MINR + i] = 0x7f800000u;                  // +inf (grid covers NPTS exactly)
}

// targets packed as (-2x, -2y, -2z, |v|^2) so dot4 = |v|^2 - 2 p.v  (3 fma)
__global__ void k_prep_verts(const float* __restrict__ ov, float4* __restrict__ v4) {
  int i = blockIdx.x * blockDim.x + threadIdx.x;
  if (i >= N_V) return;
  float x = ov[3*i], y = ov[3*i+1], z = ov[3*i+2];
  v4[i] = make_float4(-2.0f*x, -2.0f*y, -2.0f*z, fmaf(x, x, fmaf(y, y, z*z)));
}

__global__ void k_obary(const float* __restrict__ ov, const int* __restrict__ of,
                        float4* __restrict__ b4) {
  int i = blockIdx.x * blockDim.x + threadIdx.x;
  if (i >= N_F) return;
  int a = of[3*i], b = of[3*i+1], c = of[3*i+2];
  float x = (ov[3*a] + ov[3*b] + ov[3*c]) * (1.0f/3.0f);
  float y = (ov[3*a+1] + ov[3*b+1] + ov[3*c+1]) * (1.0f/3.0f);
  float z = (ov[3*a+2] + ov[3*b+2] + ov[3*c+2]) * (1.0f/3.0f);
  b4[i] = make_float4(-2.0f*x, -2.0f*y, -2.0f*z, fmaf(x, x, fmaf(y, y, z*z)));
}

__global__ void k_sbary(const float* __restrict__ sv, const int* __restrict__ sf,
                        float4* __restrict__ b4) {
  int i = blockIdx.x * blockDim.x + threadIdx.x;
  if (i >= G_F) return;
  int a = sf[3*i], b = sf[3*i+1], c = sf[3*i+2];
  float x = (sv[3*a] + sv[3*b] + sv[3*c]) * (1.0f/3.0f);
  float y = (sv[3*a+1] + sv[3*b+1] + sv[3*c+1]) * (1.0f/3.0f);
  float z = (sv[3*a+2] + sv[3*b+2] + sv[3*c+2]) * (1.0f/3.0f);
  b4[i] = make_float4(x, y, z, fmaf(x, x, fmaf(y, y, z*z)));
}

__global__ void k_pts(const float* __restrict__ sv, const int* __restrict__ sf,
                      const float* __restrict__ r1, const float* __restrict__ r2,
                      float4* __restrict__ p4) {
  int i = blockIdx.x * blockDim.x + threadIdx.x;
  if (i >= NPTS) return;
  int g = i >> 4;
  int a = sf[3*g], b = sf[3*g+1], c = sf[3*g+2];
  float sr = sqrtf(r1[i]);
  float u = 1.0f - sr;
  float v = sr * (1.0f - r2[i]);
  float w = sr * r2[i];
  float px = u*sv[3*a]   + v*sv[3*b]   + w*sv[3*c];
  float py = u*sv[3*a+1] + v*sv[3*b+1] + w*sv[3*c+1];
  float pz = u*sv[3*a+2] + v*sv[3*b+2] + w*sv[3*c+2];
  p4[i] = make_float4(px, py, pz, fmaf(px, px, fmaf(py, py, pz*pz)));
}

__device__ __forceinline__ float dot4(float4 p, float4 v) {
  return fmaf(p.x, v.x, fmaf(p.y, v.y, fmaf(p.z, v.z, v.w)));
}

// forward: min over N_F orig barycenters for each of G_F simp barycenters.
// P=2 points/thread, KS_FWD-way k-split, uint-bit atomicMin combine.
__global__ __launch_bounds__(256, 8) void k_fwd(const float4* __restrict__ ob,
                                                const float4* __restrict__ sb,
                                                unsigned int* __restrict__ minf) {
  int base = blockIdx.x * 512 + threadIdx.x;
  float4 p0 = sb[base];
  float4 p1 = sb[base + 256];
  int k0 = blockIdx.y * (N_F / KS_FWD);
  float inf = __uint_as_float(0x7f800000u);
  float m0 = inf, m1 = inf;
  for (int k = k0; k < k0 + N_F / KS_FWD; k += 2) {
    float4 va = ob[k];      // wave-uniform -> s_load_dwordx4
    float4 vb = ob[k + 1];
    float t0a = dot4(p0, va), t0b = dot4(p0, vb);
    float t1a = dot4(p1, va), t1b = dot4(p1, vb);
    m0 = fminf(fminf(m0, t0a), t0b);   // -> v_min3_f32
    m1 = fminf(fminf(m1, t1a), t1b);
  }
  atomicMin(&minf[base],       __float_as_uint(fmaxf(p0.w + m0, 0.0f)));
  atomicMin(&minf[base + 256], __float_as_uint(fmaxf(p1.w + m1, 0.0f)));
}

// reverse: min over N_V original vertices for each of NPTS sample points.
// P=4 points/thread, KS_REV-way k-split, uint-bit atomicMin combine.
__global__ __launch_bounds__(256, 8) void k_rev(const float4* __restrict__ vv,
                                                const float4* __restrict__ pp,
                                                unsigned int* __restrict__ minr) {
  int base = blockIdx.x * 1024 + threadIdx.x;
  float4 p0 = pp[base];
  float4 p1 = pp[base + 256];
  float4 p2 = pp[base + 512];
  float4 p3 = pp[base + 768];
  int k0 = blockIdx.y * (N_V / KS_REV);
  float inf = __uint_as_float(0x7f800000u);
  float m0 = inf, m1 = inf, m2 = inf, m3 = inf;
  for (int k = k0; k < k0 + N_V / KS_REV; k += 2) {
    float4 va = vv[k];      // wave-uniform -> s_load_dwordx4, 16 KB chunk stays in sL1
    float4 vb = vv[k + 1];
    float t0a = dot4(p0, va), t0b = dot4(p0, vb);
    float t1a = dot4(p1, va), t1b = dot4(p1, vb);
    float t2a = dot4(p2, va), t2b = dot4(p2, vb);
    float t3a = dot4(p3, va), t3b = dot4(p3, vb);
    m0 = fminf(fminf(m0, t0a), t0b);
    m1 = fminf(fminf(m1, t1a), t1b);
    m2 = fminf(fminf(m2, t2a), t2b);
    m3 = fminf(fminf(m3, t3a), t3b);
  }
  atomicMin(&minr[base],       __float_as_uint(fmaxf(p0.w + m0, 0.0f)));
  atomicMin(&minr[base + 256], __float_as_uint(fmaxf(p1.w + m1, 0.0f)));
  atomicMin(&minr[base + 512], __float_as_uint(fmaxf(p2.w + m2, 0.0f)));
  atomicMin(&minr[base + 768], __float_as_uint(fmaxf(p3.w + m3, 0.0f)));
}

__device__ __forceinline__ float waveSum(float v) {
  #pragma unroll
  for (int o = 32; o > 0; o >>= 1) v += __shfl_down(v, o, 64);
  return v;
}
__device__ __forceinline__ float waveMax(float v) {
  #pragma unroll
  for (int o = 32; o > 0; o >>= 1) v = fmaxf(v, __shfl_down(v, o, 64));
  return v;
}

__global__ void k_reduce(const float* __restrict__ probs, const float* __restrict__ minf,
                         const float* __restrict__ minr, float* __restrict__ acc) {
  int tid = blockIdx.x * blockDim.x + threadIdx.x;
  int stride = gridDim.x * blockDim.x;
  float sf = 0.0f, sr = 0.0f, mx = 0.0f;
  for (int i = tid; i < NPTS; i += stride) {
    float d = sqrtf(fmaxf(minr[i], 1e-12f));
    sr = fmaf(probs[i >> 4], d, sr);
    mx = fmaxf(mx, d);
    if (i < G_F) {
      float df = sqrtf(fmaxf(minf[i], 1e-12f));
      sf = fmaf(probs[i], df, sf);
      sf = fmaf(1e-4f, 1.0f - probs[i], sf);
    }
  }
  __shared__ float lf[4], lr[4], lm[4];
  int lane = threadIdx.x & 63, wid = threadIdx.x >> 6;
  sf = waveSum(sf); sr = waveSum(sr); mx = waveMax(mx);
  if (lane == 0) { lf[wid] = sf; lr[wid] = sr; lm[wid] = mx; }
  __syncthreads();
  if (wid == 0) {
    float a = (lane < 4) ? lf[lane] : 0.0f;
    float b = (lane < 4) ? lr[lane] : 0.0f;
    float c = (lane < 4) ? lm[lane] : 0.0f;
    a = waveSum(a); b = waveSum(b); c = waveMax(c);
    if (lane == 0) {
      atomicAdd(&acc[0], a);
      atomicAdd(&acc[1], b);
      atomicMax((unsigned int*)&acc[2], __float_as_uint(c));
    }
  }
}

__global__ void k_final(const float* __restrict__ acc, float* __restrict__ out) {
  float maxd = acc[2] + 1e-8f;
  out[0] = acc[0] + acc[1] * 0.1f / maxd;
}

extern "C" void kernel_launch(void* const* d_in, const int* in_sizes, int n_in,
                              void* d_out, int out_size, void* d_ws, size_t ws_size,
                              hipStream_t stream) {
  const float* ov    = (const float*)d_in[0];
  const int*   of    = (const int*)  d_in[1];
  const float* sv    = (const float*)d_in[2];
  const int*   sfc   = (const int*)  d_in[3];
  const float* probs = (const float*)d_in[4];
  const float* r1    = (const float*)d_in[5];
  const float* r2    = (const float*)d_in[6];
  float*  ws  = (float*)d_ws;
  float4* ws4 = (float4*)d_ws;
  float*  out = (float*)d_out;

  float*        acc   = ws;                 // 4 floats
  float4*       v4    = ws4 + WS_VERT;
  float4*       ob    = ws4 + WS_OBARY;
  float4*       sb    = ws4 + WS_SBARY;
  float4*       pp    = ws4 + WS_PTS;
  unsigned int* minfU = (unsigned int*)(ws + WS_MINF);
  unsigned int* minrU = (unsigned int*)(ws + WS_MINR);
  const float*  minfF = ws + WS_MINF;
  const float*  minrF = ws + WS_MINR;

  k_init<<<NPTS/256, 256, 0, stream>>>((unsigned int*)ws);
  k_prep_verts<<<N_V/256, 256, 0, stream>>>(ov, v4);
  k_obary<<<N_F/256, 256, 0, stream>>>(ov, of, ob);
  k_sbary<<<G_F/256, 256, 0, stream>>>(sv, sfc, sb);
  k_pts<<<NPTS/256, 256, 0, stream>>>(sv, sfc, r1, r2, pp);
  k_fwd<<<dim3(G_F/512, KS_FWD), 256, 0, stream>>>(ob, sb, minfU);
  k_rev<<<dim3(NPTS/1024, KS_REV), 256, 0, stream>>>(v4, pp, minrU);
  k_reduce<<<256, 256, 0, stream>>>(probs, minfF, minrF, acc);
  k_final<<<1, 1, 0, stream>>>(acc, out);
}